// Round 13
// baseline (33.209 us; speedup 1.0000x reference)
//
#include <hip/hip_runtime.h>
#include <math.h>

namespace {
constexpr int P = 4096, O = 32, H = 26, V = 48;
constexpr float EPSV = 1e-4f;   // strict < EPSV == numpy's (f32 <= 1e-4 f64)

// d_ws layout (float offsets). All bases 64B-aligned.
constexpr int AB_OFF = 0;       // [o][H][4]  {a0,a1,a2,b}          3328 f
constexpr int ED_OFF = 4096;    // [o][V][8]  {v1,inv | e,nci}     12288 f
constexpr int G_OFF  = 16384;   // [o][H][32] Gram row, pitch 32   26624 f
}

// ---- prep: build wave-uniform tables in global scratch (one block per o) ----
__global__ __launch_bounds__(256) void prep_kernel(
    const float* __restrict__ hA, const float* __restrict__ hb,
    const float* __restrict__ v1g, const float* __restrict__ v2g,
    float* __restrict__ ws)
{
    const int o = blockIdx.x;
    const int t = threadIdx.x;

    if (t < H) {
        const float* a = hA + (o * H + t) * 3;
        *reinterpret_cast<float4*>(ws + AB_OFF + (o * H + t) * 4) =
            make_float4(a[0], a[1], a[2], hb[o * H + t]);
    }
    if (t >= 64 && t < 64 + V) {
        const int v = t - 64;
        const float* A1 = v1g + (o * V + v) * 3;
        const float* A2 = v2g + (o * V + v) * 3;
        const float x0 = A1[0], x1 = A1[1], x2 = A1[2];
        const float e0 = __fsub_rn(A2[0], x0);
        const float e1 = __fsub_rn(A2[1], x1);
        const float e2 = __fsub_rn(A2[2], x2);
        const float den = __fadd_rn(__fadd_rn(__fmul_rn(e0, e0), __fmul_rn(e1, e1)),
                                    __fmul_rn(e2, e2));
        const float inv = __fdiv_rn(1.f, den);
        const float cv  = __fadd_rn(__fadd_rn(__fmul_rn(x0, e0), __fmul_rn(x1, e1)),
                                    __fmul_rn(x2, e2));
        const float nci = -__fmul_rn(cv, inv);
        float* e8 = ws + ED_OFF + (o * V + v) * 8;
        *reinterpret_cast<float4*>(e8)     = make_float4(x0, x1, x2, inv);
        *reinterpret_cast<float4*>(e8 + 4) = make_float4(e0, e1, e2, nci);
    }
    for (int e = t; e < H * H; e += 256) {
        const int h = e / H;
        const int j = e - h * H;
        const float* a = hA + (o * H + h) * 3;
        const float* c = hA + (o * H + j) * 3;
        ws[G_OFF + (o * H + h) * 32 + j] =
            __fadd_rn(__fadd_rn(__fmul_rn(a[0], c[0]), __fmul_rn(a[1], c[1])),
                      __fmul_rn(a[2], c[2]));
    }
}

// ---- main: one thread per (p,o); all tables read at wave-uniform global
// addresses -> compiler scalarizes to s_load, operands fold as SGPRs into
// VALU. No LDS, no __syncthreads. Arithmetic bit-identical to R11:
// s_j exact reference rounding; t_j = fmaf(nsh, G, s_j) with nsh = b - dot
// == -s_h bitwise; psq = nsh^2 * G[h][h]; one sqrt per pass (monotone);
// edge pass FMA-factored with precomputed inv / nci.
__global__ __launch_bounds__(256) void zono_kernel(
    const float* __restrict__ point,   // [P][3]
    const float* __restrict__ ws,      // tables
    float* __restrict__ dist_out,      // [P][O]
    float* __restrict__ grad_out)      // [P][O][3]
{
    const int o   = blockIdx.y;
    const int tid = threadIdx.x;
    const float* __restrict__ abt = ws + AB_OFF + o * H * 4;   // uniform base
    const float* __restrict__ edt = ws + ED_OFF + o * V * 8;
    const float* __restrict__ gt  = ws + G_OFF  + o * H * 32;

    const int p = blockIdx.x * blockDim.x + tid;
    const float p0 = point[p * 3 + 0];
    const float p1 = point[p * 3 + 1];
    const float p2 = point[p * 3 + 2];

    // ---- s_j (exact reference rounding) + argmax; is_neg == (maxv <= 0) ----
    float s[H];                          // compile-time indexed only
    float maxv = -INFINITY; int maxi = 0;
    #pragma unroll
    for (int j = 0; j < H; ++j) {
        const float a0 = abt[j * 4 + 0], a1 = abt[j * 4 + 1];
        const float a2 = abt[j * 4 + 2], bb = abt[j * 4 + 3];
        s[j] = __fsub_rn(
            __fadd_rn(__fadd_rn(__fmul_rn(p0, a0), __fmul_rn(p1, a1)),
                      __fmul_rn(p2, a2)),
            bb);
        if (s[j] > maxv) { maxv = s[j]; maxi = j; }    // first argmax
    }
    const bool is_neg = (maxv <= 0.f);

    // ---- face pass (rolled): t_j = fmaf(nsh, G[h][j], s_j), SGPR G-row ----
    float minpsq = INFINITY; int mini = 0;
    #pragma unroll 2
    for (int h = 0; h < H; ++h) {
        const float a0 = abt[h * 4 + 0], a1 = abt[h * 4 + 1];
        const float a2 = abt[h * 4 + 2], bb = abt[h * 4 + 3];
        const float dot = __fadd_rn(__fadd_rn(__fmul_rn(p0, a0), __fmul_rn(p1, a1)),
                                    __fmul_rn(p2, a2));
        const float nsh = __fsub_rn(bb, dot);           // == -s[h] bitwise

        const float* __restrict__ gr = gt + h * 32;     // uniform row
        float m0 = -INFINITY, m1 = -INFINITY, m2 = -INFINITY, m3 = -INFINITY;
        #pragma unroll
        for (int j = 0; j < 24; j += 4) {
            m0 = fmaxf(m0, __builtin_fmaf(nsh, gr[j + 0], s[j + 0]));
            m1 = fmaxf(m1, __builtin_fmaf(nsh, gr[j + 1], s[j + 1]));
            m2 = fmaxf(m2, __builtin_fmaf(nsh, gr[j + 2], s[j + 2]));
            m3 = fmaxf(m3, __builtin_fmaf(nsh, gr[j + 3], s[j + 3]));
        }
        m0 = fmaxf(m0, __builtin_fmaf(nsh, gr[24], s[24]));
        m1 = fmaxf(m1, __builtin_fmaf(nsh, gr[25], s[25]));
        const bool onz = (fmaxf(fmaxf(m0, m1), fmaxf(m2, m3)) < EPSV);

        const float psq = __fmul_rn(__fmul_rn(nsh, nsh), gr[h]);
        if (onz && psq < minpsq) { minpsq = psq; mini = h; }  // first argmin
    }
    const float minperp = __fsqrt_rn(minpsq);   // monotone: == min of sqrts

    // ---- edge pass: SGPR-fed; track (ts, idx), recompute q for winner ----
    float minesq = INFINITY; int midx = 0; float tsm = 0.f;
    #pragma unroll 2
    for (int v = 0; v < V; ++v) {
        const float* __restrict__ e8 = edt + v * 8;     // uniform
        const float vx = e8[0], vy = e8[1], vz = e8[2], inv = e8[3];
        const float ex = e8[4], ey = e8[5], ez = e8[6], nci = e8[7];
        const float dpe = __builtin_fmaf(p0, ex,
                          __builtin_fmaf(p1, ey, __fmul_rn(p2, ez)));
        const float th = __builtin_fmaf(dpe, inv, nci);
        const float ts = __builtin_amdgcn_fmed3f(th, 0.f, 1.f);
        const float g0 = __fsub_rn(p0, __builtin_fmaf(ts, ex, vx));
        const float g1 = __fsub_rn(p1, __builtin_fmaf(ts, ey, vy));
        const float g2 = __fsub_rn(p2, __builtin_fmaf(ts, ez, vz));
        const float esq = __builtin_fmaf(g0, g0,
                          __builtin_fmaf(g1, g1, __fmul_rn(g2, g2)));
        if (esq < minesq) { minesq = esq; midx = v; tsm = ts; }
    }
    const float mine = __fsqrt_rn(minesq);      // monotone: == min of sqrts

    // Winner's closest point (divergent vector loads; deterministic bits).
    const float4 V1w = *reinterpret_cast<const float4*>(edt + midx * 8);
    const float4 Ew  = *reinterpret_cast<const float4*>(edt + midx * 8 + 4);
    const float vm0 = __builtin_fmaf(tsm, Ew.x, V1w.x);
    const float vm1 = __builtin_fmaf(tsm, Ew.y, V1w.y);
    const float vm2 = __builtin_fmaf(tsm, Ew.z, V1w.z);

    // ---- select ----
    const int   fidx = is_neg ? maxi : mini;
    const float4 ga  = *reinterpret_cast<const float4*>(abt + fidx * 4);
    float dist = is_neg ? maxv : minperp;
    float g0 = ga.x, g1 = ga.y, g2 = ga.z;
    if (!is_neg && (mine < dist)) {
        dist = mine;
        g0 = __fdiv_rn(__fsub_rn(p0, vm0), mine);
        g1 = __fdiv_rn(__fsub_rn(p1, vm1), mine);
        g2 = __fdiv_rn(__fsub_rn(p2, vm2), mine);
    }

    const int idx = p * O + o;
    dist_out[idx] = dist;
    grad_out[idx * 3 + 0] = g0;
    grad_out[idx * 3 + 1] = g1;
    grad_out[idx * 3 + 2] = g2;
}

extern "C" void kernel_launch(void* const* d_in, const int* in_sizes, int n_in,
                              void* d_out, int out_size, void* d_ws, size_t ws_size,
                              hipStream_t stream) {
    const float* point = (const float*)d_in[0];
    const float* hA    = (const float*)d_in[1];
    const float* hb    = (const float*)d_in[2];
    const float* v1    = (const float*)d_in[3];
    const float* v2    = (const float*)d_in[4];
    float* out = (float*)d_out;
    float* ws  = (float*)d_ws;

    prep_kernel<<<dim3(O), dim3(256), 0, stream>>>(hA, hb, v1, v2, ws);
    zono_kernel<<<dim3(P / 256, O), dim3(256), 0, stream>>>(point, ws,
                                                            out, out + P * O);
}

// Round 14
// 17.826 us; speedup vs baseline: 1.8629x; 1.8629x over previous
//
#include <hip/hip_runtime.h>
#include <math.h>

namespace {
constexpr int P = 4096, O = 32, H = 26, V = 48;
constexpr int GPITCH = 28;            // Gram row stride (floats); 112B rows, 16B-aligned
constexpr float EPSV = 1e-4f;         // strict < EPSV == numpy's (f32 <= 1e-4 f64)
}

// clang fuses fmaxf(fmaxf(a,b),c) -> v_max3_f32 (gfx9+)
__device__ __forceinline__ float max3f(float a, float b, float c) {
    return fmaxf(fmaxf(a, b), c);
}
// clang fuses min(min(a,b),c) -> v_min3_u32
__device__ __forceinline__ unsigned min3u(unsigned a, unsigned b, unsigned c) {
    const unsigned ab = a < b ? a : b;
    return ab < c ? ab : c;
}

// One thread per (point p, object o).
// Gram trick: Appb[h][j] = s_j - s_h * G[h][j], G = A A^T in LDS.
// s_j keeps the reference's exact rounding (argmax/max_vals/is_neg exact).
// t_j = fmaf(nsh, G, s_j) with nsh = b - dot == -s_h bitwise; max via
// v_max3 chains (exact reassociation); psq = nsh^2 * G[h][h]; one sqrt per
// pass (correctly-rounded sqrt is monotone).
// Edge pass: packed-uint argmin u = (bits(esq)&~63)|v reduced with v_min3_u32;
// winner's ts/q/esq recomputed once (deterministic -> bitwise equal).
// Face loop stays ROLLED (R10: full unroll -> 256 VGPR + 177MB spill).
__global__ __launch_bounds__(256) void zono_kernel(
    const float* __restrict__ point,   // [P][3]
    const float* __restrict__ hA,      // [O][H][3]
    const float* __restrict__ hb,      // [O][H]
    const float* __restrict__ v1g,     // [O][V][3]
    const float* __restrict__ v2g,     // [O][V][3]
    float* __restrict__ dist_out,      // [P][O]
    float* __restrict__ grad_out)      // [P][O][3]
{
    __shared__ float4 sAb[H];            // {a0,a1,a2,b}
    __shared__ float  sG[H][GPITCH];     // Gram a_h . a_j
    __shared__ float4 sV1[V];            // {v1_0,v1_1,v1_2, inv_den}
    __shared__ float4 sE[V];             // {e0,e1,e2, -(v1.e)*inv_den}

    const int o   = blockIdx.y;
    const int tid = threadIdx.x;

    if (tid < H) {
        const float* a = hA + (o * H + tid) * 3;
        sAb[tid] = make_float4(a[0], a[1], a[2], hb[o * H + tid]);
    } else if (tid >= 32 && tid < 32 + V) {
        const int v = tid - 32;
        const float* A1 = v1g + (o * V + v) * 3;
        const float* A2 = v2g + (o * V + v) * 3;
        const float x0 = A1[0], x1 = A1[1], x2 = A1[2];
        const float e0 = __fsub_rn(A2[0], x0);
        const float e1 = __fsub_rn(A2[1], x1);
        const float e2 = __fsub_rn(A2[2], x2);
        const float den = __fadd_rn(__fadd_rn(__fmul_rn(e0, e0), __fmul_rn(e1, e1)),
                                    __fmul_rn(e2, e2));
        const float inv = __fdiv_rn(1.f, den);
        const float cv  = __fadd_rn(__fadd_rn(__fmul_rn(x0, e0), __fmul_rn(x1, e1)),
                                    __fmul_rn(x2, e2));
        const float nci = -__fmul_rn(cv, inv);
        sV1[v] = make_float4(x0, x1, x2, inv);
        sE[v]  = make_float4(e0, e1, e2, nci);
    }
    __syncthreads();

    // Build Gram table.
    for (int e = tid; e < H * H; e += 256) {
        const int h = e / H;
        const int j = e - h * H;
        const float4 A = sAb[h];
        const float4 B = sAb[j];
        sG[h][j] = __fadd_rn(__fadd_rn(__fmul_rn(A.x, B.x), __fmul_rn(A.y, B.y)),
                             __fmul_rn(A.z, B.z));
    }
    __syncthreads();

    const int p = blockIdx.x * blockDim.x + tid;
    const float p0 = point[p * 3 + 0];
    const float p1 = point[p * 3 + 1];
    const float p2 = point[p * 3 + 2];

    // ---- s_j (exact reference rounding) + argmax; is_neg == (maxv <= 0) ----
    float s[H];                          // compile-time indexed only
    float maxv = -INFINITY; int maxi = 0;
    #pragma unroll
    for (int j = 0; j < H; ++j) {
        const float4 ab = sAb[j];
        s[j] = __fsub_rn(
            __fadd_rn(__fadd_rn(__fmul_rn(p0, ab.x), __fmul_rn(p1, ab.y)),
                      __fmul_rn(p2, ab.z)),
            ab.w);
        if (s[j] > maxv) { maxv = s[j]; maxi = j; }    // first argmax
    }
    const bool is_neg = (maxv <= 0.f);

    // ---- face pass (ROLLED): t_j = fmaf(nsh, G[h][j], s_j), max3 chains ----
    float minpsq = INFINITY; int mini = 0;
    for (int h = 0; h < H; ++h) {
        const float4 ab = sAb[h];                       // broadcast LDS read
        const float dot = __fadd_rn(__fadd_rn(__fmul_rn(p0, ab.x),
                                              __fmul_rn(p1, ab.y)),
                                    __fmul_rn(p2, ab.z));
        const float nsh = __fsub_rn(ab.w, dot);         // == -s[h] bitwise

        const float4* gRow = reinterpret_cast<const float4*>(&sG[h][0]);
        float m0 = -INFINITY, m1 = -INFINITY;
        #pragma unroll
        for (int q = 0; q < 6; ++q) {                    // j = 0..23
            const float4 g = gRow[q];
            const float t0 = __builtin_fmaf(nsh, g.x, s[4 * q + 0]);
            const float t1 = __builtin_fmaf(nsh, g.y, s[4 * q + 1]);
            const float t2 = __builtin_fmaf(nsh, g.z, s[4 * q + 2]);
            const float t3 = __builtin_fmaf(nsh, g.w, s[4 * q + 3]);
            m0 = max3f(t0, t1, m0);
            m1 = max3f(t2, t3, m1);
        }
        {
            const float2 g = *reinterpret_cast<const float2*>(&sG[h][24]);
            const float t24 = __builtin_fmaf(nsh, g.x, s[24]);
            const float t25 = __builtin_fmaf(nsh, g.y, s[25]);
            m0 = max3f(t24, t25, m0);
        }
        const bool onz = (fmaxf(m0, m1) < EPSV);

        const float psq = __fmul_rn(__fmul_rn(nsh, nsh), sG[h][h]);
        if (onz && psq < minpsq) { minpsq = psq; mini = h; }  // first argmin
    }
    const float minperp = __fsqrt_rn(minpsq);   // monotone: == min of sqrts

    // ---- edge pass: packed-uint argmin, pairs folded via v_min3_u32 ----
    unsigned umin = 0xFFFFFFFFu;
    #pragma unroll 2
    for (int v = 0; v < V; v += 2) {
        unsigned ua, ub;
        {
            const float4 V1 = sV1[v];
            const float4 E  = sE[v];
            const float dpe = __builtin_fmaf(p0, E.x,
                              __builtin_fmaf(p1, E.y, __fmul_rn(p2, E.z)));
            const float th = __builtin_fmaf(dpe, V1.w, E.w);
            const float ts = __builtin_amdgcn_fmed3f(th, 0.f, 1.f);
            const float g0 = __fsub_rn(p0, __builtin_fmaf(ts, E.x, V1.x));
            const float g1 = __fsub_rn(p1, __builtin_fmaf(ts, E.y, V1.y));
            const float g2 = __fsub_rn(p2, __builtin_fmaf(ts, E.z, V1.z));
            const float esq = __builtin_fmaf(g0, g0,
                              __builtin_fmaf(g1, g1, __fmul_rn(g2, g2)));
            ua = (__float_as_uint(esq) & ~63u) | (unsigned)v;
        }
        {
            const float4 V1 = sV1[v + 1];
            const float4 E  = sE[v + 1];
            const float dpe = __builtin_fmaf(p0, E.x,
                              __builtin_fmaf(p1, E.y, __fmul_rn(p2, E.z)));
            const float th = __builtin_fmaf(dpe, V1.w, E.w);
            const float ts = __builtin_amdgcn_fmed3f(th, 0.f, 1.f);
            const float g0 = __fsub_rn(p0, __builtin_fmaf(ts, E.x, V1.x));
            const float g1 = __fsub_rn(p1, __builtin_fmaf(ts, E.y, V1.y));
            const float g2 = __fsub_rn(p2, __builtin_fmaf(ts, E.z, V1.z));
            const float esq = __builtin_fmaf(g0, g0,
                              __builtin_fmaf(g1, g1, __fmul_rn(g2, g2)));
            ub = (__float_as_uint(esq) & ~63u) | (unsigned)(v + 1);
        }
        umin = min3u(ua, ub, umin);
    }
    const int midx = (int)(umin & 63u);

    // Winner recompute (same ops/inputs as in-loop -> bitwise identical).
    const float4 V1w = sV1[midx];
    const float4 Ew  = sE[midx];
    const float dpew = __builtin_fmaf(p0, Ew.x,
                       __builtin_fmaf(p1, Ew.y, __fmul_rn(p2, Ew.z)));
    const float thw = __builtin_fmaf(dpew, V1w.w, Ew.w);
    const float tsw = __builtin_amdgcn_fmed3f(thw, 0.f, 1.f);
    const float vm0 = __builtin_fmaf(tsw, Ew.x, V1w.x);
    const float vm1 = __builtin_fmaf(tsw, Ew.y, V1w.y);
    const float vm2 = __builtin_fmaf(tsw, Ew.z, V1w.z);
    const float w0 = __fsub_rn(p0, vm0);
    const float w1 = __fsub_rn(p1, vm1);
    const float w2 = __fsub_rn(p2, vm2);
    const float esqw = __builtin_fmaf(w0, w0,
                       __builtin_fmaf(w1, w1, __fmul_rn(w2, w2)));
    const float mine = __fsqrt_rn(esqw);        // == min_v sqrt(esq_v) bitwise

    // ---- select ----
    const int   fidx = is_neg ? maxi : mini;
    const float4 ga  = sAb[fidx];
    float dist = is_neg ? maxv : minperp;
    float g0 = ga.x, g1 = ga.y, g2 = ga.z;
    if (!is_neg && (mine < dist)) {
        dist = mine;
        g0 = __fdiv_rn(w0, mine);
        g1 = __fdiv_rn(w1, mine);
        g2 = __fdiv_rn(w2, mine);
    }

    const int idx = p * O + o;
    dist_out[idx] = dist;
    grad_out[idx * 3 + 0] = g0;
    grad_out[idx * 3 + 1] = g1;
    grad_out[idx * 3 + 2] = g2;
}

extern "C" void kernel_launch(void* const* d_in, const int* in_sizes, int n_in,
                              void* d_out, int out_size, void* d_ws, size_t ws_size,
                              hipStream_t stream) {
    const float* point = (const float*)d_in[0];
    const float* hA    = (const float*)d_in[1];
    const float* hb    = (const float*)d_in[2];
    const float* v1    = (const float*)d_in[3];
    const float* v2    = (const float*)d_in[4];
    float* out = (float*)d_out;

    dim3 grid(P / 256, O);
    zono_kernel<<<grid, dim3(256), 0, stream>>>(point, hA, hb, v1, v2,
                                                out, out + P * O);
}